// Round 1
// baseline (1722.540 us; speedup 1.0000x reference)
//
#include <hip/hip_runtime.h>
#include <hip/hip_bf16.h>
#include <cstdint>
#include <cstddef>

typedef __bf16 bf16_t;
typedef __bf16 bf16x4 __attribute__((ext_vector_type(4)));
typedef __bf16 bf16x8 __attribute__((ext_vector_type(8)));
typedef float  f32x4  __attribute__((ext_vector_type(4)));

#define L_DIM 2048
#define N_DIM 8
#define E_DIM 2048
#define H_DIM 8192
#define T_DIM (L_DIM * N_DIM)   // 16384 tokens

// ---------------------------------------------------------------------------
// fp32 -> bf16 conversion, 4 elements / thread / iter (float4 loads, 8B stores)
// ---------------------------------------------------------------------------
__global__ __launch_bounds__(256) void cvt_f32_bf16(const float* __restrict__ in,
                                                    bf16_t* __restrict__ out,
                                                    int n4) {
    int stride = gridDim.x * blockDim.x;
    for (int i = blockIdx.x * blockDim.x + threadIdx.x; i < n4; i += stride) {
        float4 v = *(const float4*)(in + (size_t)i * 4);
        bf16x4 o;
        o[0] = (bf16_t)v.x; o[1] = (bf16_t)v.y;
        o[2] = (bf16_t)v.z; o[3] = (bf16_t)v.w;
        *(bf16x4*)(out + (size_t)i * 4) = o;
    }
}

// ---------------------------------------------------------------------------
// C[M,N] = A[M,K] * B[N,K]^T  (both row-major, K contiguous), bf16 in, f32 acc.
// m97 structure: 128x128 tile, BK=32, 4 waves (2x2) of 64x64, global_load_lds
// width=16 staging, 2 barriers per K-step, XCD-bijective swizzle.
// GELU_OUT=true : C = bf16( GELU(acc + bias[col]) )    (h for GEMM2)
// GELU_OUT=false: C = f32 ( acc + bias[col] )          (final output)
// M,N,K all multiples of 128 here -> no bounds checks.
// ---------------------------------------------------------------------------
template <bool GELU_OUT>
__global__ __launch_bounds__(256) void gemm_bt(const bf16_t* __restrict__ A,
                                               const bf16_t* __restrict__ B,
                                               const float* __restrict__ bias,
                                               void* __restrict__ Cout,
                                               int M, int N, int K) {
    constexpr int BM = 128, BN = 128, BK = 32;
    __shared__ bf16_t sA[BM * BK];   // 8 KB
    __shared__ bf16_t sB[BN * BK];   // 8 KB

    const int tid  = threadIdx.x;
    const int lane = tid & 63;
    const int wid  = tid >> 6;

    // XCD-aware bijective block swizzle (nwg % 8 == 0 for all our shapes)
    const int nTn = N / BN;
    const int nwg = (M / BM) * nTn;
    const int q   = nwg >> 3;
    const int wg  = (blockIdx.x & 7) * q + (blockIdx.x >> 3);
    const int tm  = wg / nTn;
    const int tn  = wg % nTn;
    const size_t rowBase = (size_t)tm * BM;
    const size_t colBase = (size_t)tn * BN;

    const int wr = wid >> 1;   // wave row (0..1) -> 64-row block
    const int wc = wid & 1;    // wave col (0..1) -> 64-col block

    f32x4 acc[4][4] = {};

    // Staging: each K-step moves A-tile (8KB) + B-tile (8KB).
    // 16B chunks: 512 per tile; 256 threads x 2 iterations.
    const int frow = lane & 15;        // fragment row within 16
    const int koff = (lane >> 4) * 8;  // fragment k offset (8 contiguous bf16)

    for (int k0 = 0; k0 < K; k0 += BK) {
#pragma unroll
        for (int t = 0; t < 2; ++t) {
            const int cbase = t * 256 + wid * 64;  // wave-uniform chunk base
            const int c     = cbase + lane;        // this lane's chunk
            const int r     = c >> 2;              // tile row (4 chunks/row)
            const int cc    = (c & 3) * 8;         // k element offset in row
            const bf16_t* ga = A + (rowBase + r) * (size_t)K + k0 + cc;
            const bf16_t* gb = B + (colBase + r) * (size_t)K + k0 + cc;
            // LDS dest must be wave-uniform; HW adds lane*16.
            __builtin_amdgcn_global_load_lds(
                (const __attribute__((address_space(1))) void*)ga,
                (__attribute__((address_space(3))) void*)(sA + cbase * 8), 16, 0, 0);
            __builtin_amdgcn_global_load_lds(
                (const __attribute__((address_space(1))) void*)gb,
                (__attribute__((address_space(3))) void*)(sB + cbase * 8), 16, 0, 0);
        }
        __syncthreads();   // compiler emits vmcnt(0) drain before barrier

        bf16x8 af[4], bfr[4];
#pragma unroll
        for (int m = 0; m < 4; ++m)
            af[m] = *(const bf16x8*)(sA + (wr * 64 + m * 16 + frow) * BK + koff);
#pragma unroll
        for (int n = 0; n < 4; ++n)
            bfr[n] = *(const bf16x8*)(sB + (wc * 64 + n * 16 + frow) * BK + koff);

#pragma unroll
        for (int m = 0; m < 4; ++m)
#pragma unroll
            for (int n = 0; n < 4; ++n)
                acc[m][n] = __builtin_amdgcn_mfma_f32_16x16x32_bf16(
                    af[m], bfr[n], acc[m][n], 0, 0, 0);
        __syncthreads();
    }

    // Epilogue. C/D layout (verified m89/m91): col = lane&15, row = (lane>>4)*4 + j
    const int orow = (lane >> 4) * 4;
    const int ocol = lane & 15;
#pragma unroll
    for (int m = 0; m < 4; ++m) {
#pragma unroll
        for (int n = 0; n < 4; ++n) {
            const size_t col = colBase + wc * 64 + n * 16 + ocol;
            const float bv = bias[col];
#pragma unroll
            for (int j = 0; j < 4; ++j) {
                const size_t row = rowBase + wr * 64 + m * 16 + orow + j;
                float v = acc[m][n][j] + bv;
                if constexpr (GELU_OUT) {
                    // exact GELU: 0.5*x*(1+erf(x/sqrt(2)))
                    float g = 0.5f * v * (1.0f + erff(v * 0.70710678118654752f));
                    ((bf16_t*)Cout)[row * (size_t)N + col] = (bf16_t)g;
                } else {
                    ((float*)Cout)[row * (size_t)N + col] = v;
                }
            }
        }
    }
}

// ---------------------------------------------------------------------------
extern "C" void kernel_launch(void* const* d_in, const int* in_sizes, int n_in,
                              void* d_out, int out_size, void* d_ws, size_t ws_size,
                              hipStream_t stream) {
    const float* x  = (const float*)d_in[0];  // [L,N,E] = [16384, 2048]
    const float* p1 = (const float*)d_in[1];  // [H,E]   = [8192, 2048]
    const float* b1 = (const float*)d_in[2];  // [H]
    const float* p2 = (const float*)d_in[3];  // [E,H]   = [2048, 8192]
    const float* b2 = (const float*)d_in[4];  // [E]
    // d_in[5] = gate_w, unused (routing is identity on the output)
    float* out = (float*)d_out;               // [16384, 2048] f32

    char* ws = (char*)d_ws;
    bf16_t* xb  = (bf16_t*)(ws);                          // 64 MB
    bf16_t* p1b = (bf16_t*)(ws + ((size_t)64 << 20));     // 32 MB
    bf16_t* p2b = (bf16_t*)(ws + ((size_t)96 << 20));     // 32 MB
    bf16_t* h   = (bf16_t*)(ws + ((size_t)128 << 20));    // 256 MB

    cvt_f32_bf16<<<2048, 256, 0, stream>>>(x,  xb,  (T_DIM * E_DIM) / 4);
    cvt_f32_bf16<<<1024, 256, 0, stream>>>(p1, p1b, (H_DIM * E_DIM) / 4);
    cvt_f32_bf16<<<1024, 256, 0, stream>>>(p2, p2b, (E_DIM * H_DIM) / 4);

    // GEMM1: [T,E] x [H,E]^T -> h[T,H], fused bias+GELU, bf16 out
    gemm_bt<true><<<(T_DIM / 128) * (H_DIM / 128), 256, 0, stream>>>(
        xb, p1b, b1, (void*)h, T_DIM, H_DIM, E_DIM);

    // GEMM2: [T,H] x [E,H]^T -> out[T,E], fused bias, f32 out
    gemm_bt<false><<<(T_DIM / 128) * (E_DIM / 128), 256, 0, stream>>>(
        h, p2b, b2, (void*)out, T_DIM, E_DIM, H_DIM);
}

// Round 2
// 1150.269 us; speedup vs baseline: 1.4975x; 1.4975x over previous
//
#include <hip/hip_runtime.h>
#include <hip/hip_bf16.h>
#include <cstdint>
#include <cstddef>

typedef __bf16 bf16_t;
typedef __bf16 bf16x4 __attribute__((ext_vector_type(4)));
typedef __bf16 bf16x8 __attribute__((ext_vector_type(8)));
typedef float  f32x4  __attribute__((ext_vector_type(4)));

#define L_DIM 2048
#define N_DIM 8
#define E_DIM 2048
#define H_DIM 8192
#define T_DIM (L_DIM * N_DIM)   // 16384 tokens

// ---------------------------------------------------------------------------
// fp32 -> bf16 conversion
// ---------------------------------------------------------------------------
__global__ __launch_bounds__(256) void cvt_f32_bf16(const float* __restrict__ in,
                                                    bf16_t* __restrict__ out,
                                                    int n4) {
    int stride = gridDim.x * blockDim.x;
    for (int i = blockIdx.x * blockDim.x + threadIdx.x; i < n4; i += stride) {
        float4 v = *(const float4*)(in + (size_t)i * 4);
        bf16x4 o;
        o[0] = (bf16_t)v.x; o[1] = (bf16_t)v.y;
        o[2] = (bf16_t)v.z; o[3] = (bf16_t)v.w;
        *(bf16x4*)(out + (size_t)i * 4) = o;
    }
}

// ---------------------------------------------------------------------------
// 256x256 8-phase GEMM (m201 template, plain HIP).
// C[M,N] = A[M,K] * B[N,K]^T, bf16 in, f32 acc.
// 512 threads = 8 waves (2 Mwaves x 4 Nwaves), per-wave output 128x64.
// LDS 128KB: 2 dbuf x (A 256x64 + B 256x64) bf16. BK=64, 4 phases/K-tile.
// Staging: 1 half-tile (128 rows x 64 cols = 16KB) per phase via
// 2 global_load_lds(16B) per wave; counted vmcnt(6) once per K-tile.
// LDS swizzle: physical slot = logical slot ^ (row & 7)  (16B slots, 128B rows)
// applied on BOTH the pre-swizzled global source and the ds_read address.
// Wave wr owns M rows {64p + 32*wr .. +31} per phase p -> A consumed in
// 64-row stripes in phase order, making the staggered staging race-free.
// ---------------------------------------------------------------------------
template <bool GELU_OUT>
__global__ __launch_bounds__(512, 2) void gemm256(const bf16_t* __restrict__ Am,
                                                  const bf16_t* __restrict__ Bm,
                                                  const float* __restrict__ bias,
                                                  void* __restrict__ Cout,
                                                  int M, int N, int K) {
    extern __shared__ char lds[];
    constexpr int BM = 256, BN = 256, BK = 64;
    const int NT = K / BK;

    const int tid  = threadIdx.x;
    const int lane = tid & 63;
    const int wid  = tid >> 6;
    const int wr   = wid >> 2;   // 0..1
    const int wc   = wid & 3;    // 0..3

    // XCD-aware bijective swizzle (nwg % 8 == 0 for all shapes here)
    const int nTn = N / BN;
    const int nwg = (M / BM) * nTn;
    const int q   = nwg >> 3;
    const int wg  = (blockIdx.x & 7) * q + (blockIdx.x >> 3);
    const size_t rowBase = (size_t)(wg / nTn) * BM;
    const size_t colBase = (size_t)(wg % nTn) * BN;

    // staging lane geometry: unit u = (j*8+wid)*64 + lane covers 16B;
    // row_in_half = j*64 + wid*8 + (lane>>3), phys slot = lane&7,
    // logical col slot = (lane&7) ^ (lane>>3)   [row&7 == lane>>3]
    const int srow  = wid * 8 + (lane >> 3);
    const int scol8 = ((lane & 7) ^ (lane >> 3)) * 8;

    auto STAGE = [&](int isB, int half, int slot) {
        const int kt_ = (slot < NT) ? slot : (NT - 1);     // clamp tail (dummy, never read)
        const unsigned reg_ = (unsigned)((slot & 1) * 65536 + isB * 32768 + half * 16384);
        const bf16_t* gbase_ = isB ? Bm : Am;
        const size_t gr_ = (isB ? colBase : rowBase) + (size_t)(half * 128 + srow);
        const bf16_t* s0 = gbase_ + gr_ * (size_t)K + (size_t)(kt_ * 64 + scol8);
        __builtin_amdgcn_global_load_lds(
            (const __attribute__((address_space(1))) void*)s0,
            (__attribute__((address_space(3))) void*)(lds + reg_ + (unsigned)(wid * 1024)),
            16, 0, 0);
        __builtin_amdgcn_global_load_lds(
            (const __attribute__((address_space(1))) void*)(s0 + (size_t)64 * K),
            (__attribute__((address_space(3))) void*)(lds + reg_ + (unsigned)((8 + wid) * 1024)),
            16, 0, 0);
    };

    // M-frag m of wave wr -> tile row (m>>1)*64 + wr*32 + (m&1)*16
    auto ldsA = [&](unsigned bufo, int m, int kk) -> bf16x8 {
        const int row  = (m >> 1) * 64 + wr * 32 + (m & 1) * 16 + (lane & 15);
        const int slot = ((kk << 2) + (lane >> 4)) ^ (lane & 7);
        return *(const bf16x8*)(lds + bufo + row * 128 + slot * 16);
    };
    auto ldsB = [&](unsigned bufo, int n, int kk) -> bf16x8 {
        const int row  = wc * 64 + n * 16 + (lane & 15);
        const int slot = ((kk << 2) + (lane >> 4)) ^ (lane & 7);
        return *(const bf16x8*)(lds + bufo + 32768 + row * 128 + slot * 16);
    };

    f32x4 acc[8][4] = {};

    // Prologue: K-tile 0 complete (B0,B1,A0,A1) + K-tile 1 partial (B0,B1,A0)
    STAGE(1, 0, 0); STAGE(1, 1, 0); STAGE(0, 0, 0); STAGE(0, 1, 0);
    STAGE(1, 0, 1); STAGE(1, 1, 1); STAGE(0, 0, 1);
    asm volatile("s_waitcnt vmcnt(6)" ::: "memory");   // K-tile 0 landed
    __builtin_amdgcn_s_barrier();

    for (int t = 0; t < NT; ++t) {
        const unsigned cur = (unsigned)(t & 1) * 65536u;
        bf16x8 bf[4][2];
        bf16x8 af[2][2];

        // ---- phase 0: all B (8 reads) + A m=0,1 (4 reads); stage A1(t+1) ----
#pragma unroll
        for (int n = 0; n < 4; ++n)
#pragma unroll
            for (int kk = 0; kk < 2; ++kk)
                bf[n][kk] = ldsB(cur, n, kk);
#pragma unroll
        for (int mm = 0; mm < 2; ++mm)
#pragma unroll
            for (int kk = 0; kk < 2; ++kk)
                af[mm][kk] = ldsA(cur, mm, kk);
        STAGE(0, 1, t + 1);
        asm volatile("s_waitcnt lgkmcnt(8)" ::: "memory");
        __builtin_amdgcn_s_barrier();
        asm volatile("s_waitcnt lgkmcnt(0)" ::: "memory");
        __builtin_amdgcn_s_setprio(1);
#pragma unroll
        for (int mm = 0; mm < 2; ++mm)
#pragma unroll
            for (int n = 0; n < 4; ++n)
#pragma unroll
                for (int kk = 0; kk < 2; ++kk)
                    acc[mm][n] = __builtin_amdgcn_mfma_f32_16x16x32_bf16(
                        af[mm][kk], bf[n][kk], acc[mm][n], 0, 0, 0);
        __builtin_amdgcn_s_setprio(0);
        __builtin_amdgcn_s_barrier();

        // ---- phases 1..3: A m=2p,2p+1; stage B0/B1/A0 of (t+2) ----
#pragma unroll
        for (int ph = 1; ph < 4; ++ph) {
#pragma unroll
            for (int mm = 0; mm < 2; ++mm)
#pragma unroll
                for (int kk = 0; kk < 2; ++kk)
                    af[mm][kk] = ldsA(cur, ph * 2 + mm, kk);
            if (ph == 1)      STAGE(1, 0, t + 2);
            else if (ph == 2) STAGE(1, 1, t + 2);
            else {            STAGE(0, 0, t + 2);
                              asm volatile("s_waitcnt vmcnt(6)" ::: "memory"); }
            __builtin_amdgcn_s_barrier();
            asm volatile("s_waitcnt lgkmcnt(0)" ::: "memory");
            __builtin_amdgcn_s_setprio(1);
#pragma unroll
            for (int mm = 0; mm < 2; ++mm)
#pragma unroll
                for (int n = 0; n < 4; ++n)
#pragma unroll
                    for (int kk = 0; kk < 2; ++kk)
                        acc[ph * 2 + mm][n] = __builtin_amdgcn_mfma_f32_16x16x32_bf16(
                            af[mm][kk], bf[n][kk], acc[ph * 2 + mm][n], 0, 0, 0);
            __builtin_amdgcn_s_setprio(0);
            __builtin_amdgcn_s_barrier();
        }
    }
    asm volatile("s_waitcnt vmcnt(0)" ::: "memory");   // drain tail dummy loads

    // Epilogue. C/D layout: col = lane&15, row = (lane>>4)*4 + j
    const int orow = (lane >> 4) * 4;
    const int ocol = lane & 15;
#pragma unroll
    for (int m = 0; m < 8; ++m) {
        const size_t rb = rowBase + (size_t)((m >> 1) * 64 + wr * 32 + (m & 1) * 16 + orow);
#pragma unroll
        for (int n = 0; n < 4; ++n) {
            const size_t col = colBase + (size_t)(wc * 64 + n * 16 + ocol);
            const float bv = bias[col];
#pragma unroll
            for (int j = 0; j < 4; ++j) {
                float v = acc[m][n][j] + bv;
                if constexpr (GELU_OUT) {
                    float g = 0.5f * v * (1.0f + erff(v * 0.70710678118654752f));
                    ((bf16_t*)Cout)[(rb + j) * (size_t)N + col] = (bf16_t)g;
                } else {
                    ((float*)Cout)[(rb + j) * (size_t)N + col] = v;
                }
            }
        }
    }
}

// ---------------------------------------------------------------------------
extern "C" void kernel_launch(void* const* d_in, const int* in_sizes, int n_in,
                              void* d_out, int out_size, void* d_ws, size_t ws_size,
                              hipStream_t stream) {
    const float* x  = (const float*)d_in[0];  // [16384, 2048]
    const float* p1 = (const float*)d_in[1];  // [8192, 2048]
    const float* b1 = (const float*)d_in[2];  // [8192]
    const float* p2 = (const float*)d_in[3];  // [2048, 8192]
    const float* b2 = (const float*)d_in[4];  // [2048]
    // d_in[5] = gate_w, unused (routing is identity on the output)
    float* out = (float*)d_out;

    char* ws = (char*)d_ws;
    bf16_t* xb  = (bf16_t*)(ws);                          // 64 MB
    bf16_t* p1b = (bf16_t*)(ws + ((size_t)64 << 20));     // 32 MB
    bf16_t* p2b = (bf16_t*)(ws + ((size_t)96 << 20));     // 32 MB
    bf16_t* h   = (bf16_t*)(ws + ((size_t)128 << 20));    // 256 MB

    (void)hipFuncSetAttribute((const void*)gemm256<true>,
                              hipFuncAttributeMaxDynamicSharedMemorySize, 131072);
    (void)hipFuncSetAttribute((const void*)gemm256<false>,
                              hipFuncAttributeMaxDynamicSharedMemorySize, 131072);

    cvt_f32_bf16<<<2048, 256, 0, stream>>>(x,  xb,  (T_DIM * E_DIM) / 4);
    cvt_f32_bf16<<<1024, 256, 0, stream>>>(p1, p1b, (H_DIM * E_DIM) / 4);
    cvt_f32_bf16<<<1024, 256, 0, stream>>>(p2, p2b, (E_DIM * H_DIM) / 4);

    // GEMM1: [T,E] x [H,E]^T -> h[T,H], fused bias+GELU, bf16 out
    gemm256<true><<<(T_DIM / 256) * (H_DIM / 256), 512, 131072, stream>>>(
        xb, p1b, b1, (void*)h, T_DIM, H_DIM, E_DIM);

    // GEMM2: [T,H] x [E,H]^T -> out[T,E], fused bias, f32 out
    gemm256<false><<<(T_DIM / 256) * (E_DIM / 256), 512, 131072, stream>>>(
        h, p2b, b2, (void*)out, T_DIM, E_DIM, H_DIM);
}

// Round 3
// 1074.866 us; speedup vs baseline: 1.6026x; 1.0702x over previous
//
#include <hip/hip_runtime.h>
#include <hip/hip_bf16.h>
#include <cstdint>
#include <cstddef>

typedef __bf16 bf16_t;
typedef __bf16 bf16x4 __attribute__((ext_vector_type(4)));
typedef __bf16 bf16x8 __attribute__((ext_vector_type(8)));
typedef float  f32x4  __attribute__((ext_vector_type(4)));

#define L_DIM 2048
#define N_DIM 8
#define E_DIM 2048
#define H_DIM 8192
#define T_DIM (L_DIM * N_DIM)   // 16384 tokens

// ---------------------------------------------------------------------------
// fp32 -> bf16 conversion
// ---------------------------------------------------------------------------
__global__ __launch_bounds__(256) void cvt_f32_bf16(const float* __restrict__ in,
                                                    bf16_t* __restrict__ out,
                                                    int n4) {
    int stride = gridDim.x * blockDim.x;
    for (int i = blockIdx.x * blockDim.x + threadIdx.x; i < n4; i += stride) {
        float4 v = *(const float4*)(in + (size_t)i * 4);
        bf16x4 o;
        o[0] = (bf16_t)v.x; o[1] = (bf16_t)v.y;
        o[2] = (bf16_t)v.z; o[3] = (bf16_t)v.w;
        *(bf16x4*)(out + (size_t)i * 4) = o;
    }
}

// ---------------------------------------------------------------------------
// Fast GELU (tanh approximation), branch-free, HW exp2/rcp.
// gelu(x) ~= x * s / (s + 1),  s = exp2( x * (2.3022618 + 0.1029456 x^2) )
//   [constants = 2*log2(e)*0.79788456*(1, 0.044715)]
// max abs error vs exact erf-GELU ~1e-3 (< bf16 quantization of h).
// Clamp w<=60 avoids inf/inf=NaN for x>~9; large-neg x underflows s->0 -> 0.
// ---------------------------------------------------------------------------
__device__ __forceinline__ float fast_gelu(float x) {
    float x2 = x * x;
    float w  = x * __builtin_fmaf(0.1029456f, x2, 2.3022618f);
    w = fminf(w, 60.0f);
    float s = __builtin_amdgcn_exp2f(w);          // v_exp_f32
    float r = __builtin_amdgcn_rcpf(s + 1.0f);    // v_rcp_f32
    return x * s * r;
}

// ---------------------------------------------------------------------------
// 256x256 8-phase GEMM (m201 template, plain HIP).
// C[M,N] = A[M,K] * B[N,K]^T, bf16 in, f32 acc.
// 512 threads = 8 waves (2 Mwaves x 4 Nwaves), per-wave output 128x64.
// LDS 128KB: 2 dbuf x (A 256x64 + B 256x64) bf16. BK=64, 4 phases/K-tile.
// Staging: 1 half-tile (128 rows x 64 cols = 16KB) per phase via
// 2 global_load_lds(16B) per wave; counted vmcnt(6) once per K-tile.
// LDS swizzle: physical slot = logical slot ^ (row & 7)  (16B slots, 128B rows)
// applied on BOTH the pre-swizzled global source and the ds_read address.
// ---------------------------------------------------------------------------
template <bool GELU_OUT>
__global__ __launch_bounds__(512, 2) void gemm256(const bf16_t* __restrict__ Am,
                                                  const bf16_t* __restrict__ Bm,
                                                  const float* __restrict__ bias,
                                                  void* __restrict__ Cout,
                                                  int M, int N, int K) {
    extern __shared__ char lds[];
    constexpr int BM = 256, BN = 256, BK = 64;
    const int NT = K / BK;

    const int tid  = threadIdx.x;
    const int lane = tid & 63;
    const int wid  = tid >> 6;
    const int wr   = wid >> 2;   // 0..1
    const int wc   = wid & 3;    // 0..3

    // XCD-aware bijective swizzle (nwg % 8 == 0 for all shapes here)
    const int nTn = N / BN;
    const int nwg = (M / BM) * nTn;
    const int q   = nwg >> 3;
    const int wg  = (blockIdx.x & 7) * q + (blockIdx.x >> 3);
    const size_t rowBase = (size_t)(wg / nTn) * BM;
    const size_t colBase = (size_t)(wg % nTn) * BN;

    // staging lane geometry: row_in_half = wid*8 + (lane>>3), phys slot = lane&7,
    // pre-swizzled logical col slot = (lane&7) ^ (row&7)  [row&7 == lane>>3]
    const int srow  = wid * 8 + (lane >> 3);
    const int scol8 = ((lane & 7) ^ (lane >> 3)) * 8;

    auto STAGE = [&](int isB, int half, int slot) {
        const int kt_ = (slot < NT) ? slot : (NT - 1);     // clamp tail (dummy, never read)
        const unsigned reg_ = (unsigned)((slot & 1) * 65536 + isB * 32768 + half * 16384);
        const bf16_t* gbase_ = isB ? Bm : Am;
        const size_t gr_ = (isB ? colBase : rowBase) + (size_t)(half * 128 + srow);
        const bf16_t* s0 = gbase_ + gr_ * (size_t)K + (size_t)(kt_ * 64 + scol8);
        __builtin_amdgcn_global_load_lds(
            (const __attribute__((address_space(1))) void*)s0,
            (__attribute__((address_space(3))) void*)(lds + reg_ + (unsigned)(wid * 1024)),
            16, 0, 0);
        __builtin_amdgcn_global_load_lds(
            (const __attribute__((address_space(1))) void*)(s0 + (size_t)64 * K),
            (__attribute__((address_space(3))) void*)(lds + reg_ + (unsigned)((8 + wid) * 1024)),
            16, 0, 0);
    };

    // M-frag m of wave wr -> tile row (m>>1)*64 + wr*32 + (m&1)*16
    auto ldsA = [&](unsigned bufo, int m, int kk) -> bf16x8 {
        const int row  = (m >> 1) * 64 + wr * 32 + (m & 1) * 16 + (lane & 15);
        const int slot = ((kk << 2) + (lane >> 4)) ^ (lane & 7);
        return *(const bf16x8*)(lds + bufo + row * 128 + slot * 16);
    };
    auto ldsB = [&](unsigned bufo, int n, int kk) -> bf16x8 {
        const int row  = wc * 64 + n * 16 + (lane & 15);
        const int slot = ((kk << 2) + (lane >> 4)) ^ (lane & 7);
        return *(const bf16x8*)(lds + bufo + 32768 + row * 128 + slot * 16);
    };

    f32x4 acc[8][4] = {};

    // Prologue: K-tile 0 complete (B0,B1,A0,A1) + K-tile 1 partial (B0,B1,A0)
    STAGE(1, 0, 0); STAGE(1, 1, 0); STAGE(0, 0, 0); STAGE(0, 1, 0);
    STAGE(1, 0, 1); STAGE(1, 1, 1); STAGE(0, 0, 1);
    asm volatile("s_waitcnt vmcnt(6)" ::: "memory");   // K-tile 0 landed
    __builtin_amdgcn_s_barrier();

    for (int t = 0; t < NT; ++t) {
        const unsigned cur = (unsigned)(t & 1) * 65536u;
        bf16x8 bf[4][2];
        bf16x8 af[2][2];

        // ---- phase 0: all B (8 reads) + A m=0,1 (4 reads); stage A1(t+1) ----
#pragma unroll
        for (int n = 0; n < 4; ++n)
#pragma unroll
            for (int kk = 0; kk < 2; ++kk)
                bf[n][kk] = ldsB(cur, n, kk);
#pragma unroll
        for (int mm = 0; mm < 2; ++mm)
#pragma unroll
            for (int kk = 0; kk < 2; ++kk)
                af[mm][kk] = ldsA(cur, mm, kk);
        STAGE(0, 1, t + 1);
        asm volatile("s_waitcnt lgkmcnt(8)" ::: "memory");
        __builtin_amdgcn_s_barrier();
        asm volatile("s_waitcnt lgkmcnt(0)" ::: "memory");
        __builtin_amdgcn_s_setprio(1);
#pragma unroll
        for (int mm = 0; mm < 2; ++mm)
#pragma unroll
            for (int n = 0; n < 4; ++n)
#pragma unroll
                for (int kk = 0; kk < 2; ++kk)
                    acc[mm][n] = __builtin_amdgcn_mfma_f32_16x16x32_bf16(
                        af[mm][kk], bf[n][kk], acc[mm][n], 0, 0, 0);
        __builtin_amdgcn_s_setprio(0);
        __builtin_amdgcn_s_barrier();

        // ---- phases 1..3: A m=2p,2p+1; stage B0/B1/A0 of (t+2) ----
#pragma unroll
        for (int ph = 1; ph < 4; ++ph) {
#pragma unroll
            for (int mm = 0; mm < 2; ++mm)
#pragma unroll
                for (int kk = 0; kk < 2; ++kk)
                    af[mm][kk] = ldsA(cur, ph * 2 + mm, kk);
            if (ph == 1)      STAGE(1, 0, t + 2);
            else if (ph == 2) STAGE(1, 1, t + 2);
            else {            STAGE(0, 0, t + 2);
                              asm volatile("s_waitcnt vmcnt(6)" ::: "memory"); }
            __builtin_amdgcn_s_barrier();
            asm volatile("s_waitcnt lgkmcnt(0)" ::: "memory");
            __builtin_amdgcn_s_setprio(1);
#pragma unroll
            for (int mm = 0; mm < 2; ++mm)
#pragma unroll
                for (int n = 0; n < 4; ++n)
#pragma unroll
                    for (int kk = 0; kk < 2; ++kk)
                        acc[ph * 2 + mm][n] = __builtin_amdgcn_mfma_f32_16x16x32_bf16(
                            af[mm][kk], bf[n][kk], acc[ph * 2 + mm][n], 0, 0, 0);
            __builtin_amdgcn_s_setprio(0);
            __builtin_amdgcn_s_barrier();
        }
    }
    asm volatile("s_waitcnt vmcnt(0)" ::: "memory");   // drain tail dummy loads

    // Epilogue. C/D layout: col = lane&15, row = (lane>>4)*4 + j
    const int orow = (lane >> 4) * 4;
    const int ocol = lane & 15;
#pragma unroll
    for (int m = 0; m < 8; ++m) {
        const size_t rb = rowBase + (size_t)((m >> 1) * 64 + wr * 32 + (m & 1) * 16 + orow);
#pragma unroll
        for (int n = 0; n < 4; ++n) {
            const size_t col = colBase + (size_t)(wc * 64 + n * 16 + ocol);
            const float bv = bias[col];
#pragma unroll
            for (int j = 0; j < 4; ++j) {
                float v = acc[m][n][j] + bv;
                if constexpr (GELU_OUT) {
                    ((bf16_t*)Cout)[(rb + j) * (size_t)N + col] = (bf16_t)fast_gelu(v);
                } else {
                    ((float*)Cout)[(rb + j) * (size_t)N + col] = v;
                }
            }
        }
    }
}

// ---------------------------------------------------------------------------
extern "C" void kernel_launch(void* const* d_in, const int* in_sizes, int n_in,
                              void* d_out, int out_size, void* d_ws, size_t ws_size,
                              hipStream_t stream) {
    const float* x  = (const float*)d_in[0];  // [16384, 2048]
    const float* p1 = (const float*)d_in[1];  // [8192, 2048]
    const float* b1 = (const float*)d_in[2];  // [8192]
    const float* p2 = (const float*)d_in[3];  // [2048, 8192]
    const float* b2 = (const float*)d_in[4];  // [2048]
    // d_in[5] = gate_w, unused (routing is identity on the output)
    float* out = (float*)d_out;

    char* ws = (char*)d_ws;
    bf16_t* xb  = (bf16_t*)(ws);                          // 64 MB
    bf16_t* p1b = (bf16_t*)(ws + ((size_t)64 << 20));     // 32 MB
    bf16_t* p2b = (bf16_t*)(ws + ((size_t)96 << 20));     // 32 MB
    bf16_t* h   = (bf16_t*)(ws + ((size_t)128 << 20));    // 256 MB

    (void)hipFuncSetAttribute((const void*)gemm256<true>,
                              hipFuncAttributeMaxDynamicSharedMemorySize, 131072);
    (void)hipFuncSetAttribute((const void*)gemm256<false>,
                              hipFuncAttributeMaxDynamicSharedMemorySize, 131072);

    cvt_f32_bf16<<<2048, 256, 0, stream>>>(x,  xb,  (T_DIM * E_DIM) / 4);
    cvt_f32_bf16<<<1024, 256, 0, stream>>>(p1, p1b, (H_DIM * E_DIM) / 4);
    cvt_f32_bf16<<<1024, 256, 0, stream>>>(p2, p2b, (E_DIM * H_DIM) / 4);

    // GEMM1: [T,E] x [H,E]^T -> h[T,H], fused bias+GELU, bf16 out
    gemm256<true><<<(T_DIM / 256) * (H_DIM / 256), 512, 131072, stream>>>(
        xb, p1b, b1, (void*)h, T_DIM, H_DIM, E_DIM);

    // GEMM2: [T,H] x [E,H]^T -> out[T,E], fused bias, f32 out
    gemm256<false><<<(T_DIM / 256) * (E_DIM / 256), 512, 131072, stream>>>(
        h, p2b, b2, (void*)out, T_DIM, E_DIM, H_DIM);
}

// Round 4
// 1058.972 us; speedup vs baseline: 1.6266x; 1.0150x over previous
//
#include <hip/hip_runtime.h>
#include <hip/hip_bf16.h>
#include <cstdint>
#include <cstddef>

typedef __bf16 bf16_t;
typedef __bf16 bf16x4 __attribute__((ext_vector_type(4)));
typedef __bf16 bf16x8 __attribute__((ext_vector_type(8)));
typedef float  f32x4  __attribute__((ext_vector_type(4)));

#define L_DIM 2048
#define N_DIM 8
#define E_DIM 2048
#define H_DIM 8192
#define T_DIM (L_DIM * N_DIM)   // 16384 tokens

// ---------------------------------------------------------------------------
// fp32 -> bf16 conversion
// ---------------------------------------------------------------------------
__global__ __launch_bounds__(256) void cvt_f32_bf16(const float* __restrict__ in,
                                                    bf16_t* __restrict__ out,
                                                    int n4) {
    int stride = gridDim.x * blockDim.x;
    for (int i = blockIdx.x * blockDim.x + threadIdx.x; i < n4; i += stride) {
        float4 v = *(const float4*)(in + (size_t)i * 4);
        bf16x4 o;
        o[0] = (bf16_t)v.x; o[1] = (bf16_t)v.y;
        o[2] = (bf16_t)v.z; o[3] = (bf16_t)v.w;
        *(bf16x4*)(out + (size_t)i * 4) = o;
    }
}

// ---------------------------------------------------------------------------
// Fast GELU (tanh approximation), branch-free, HW exp2/rcp.
// ---------------------------------------------------------------------------
__device__ __forceinline__ float fast_gelu(float x) {
    float x2 = x * x;
    float w  = x * __builtin_fmaf(0.1029456f, x2, 2.3022618f);
    w = fminf(w, 60.0f);
    float s = __builtin_amdgcn_exp2f(w);          // v_exp_f32
    float r = __builtin_amdgcn_rcpf(s + 1.0f);    // v_rcp_f32
    return x * s * r;
}

// ---------------------------------------------------------------------------
// Persistent 256x256 8-phase GEMM (m201 template, flattened multi-tile).
// C[M,N] = A[M,K] * B[N,K]^T, bf16 in, f32 acc. Grid = 256 blocks exactly;
// block b handles ntile=2^lgNtile consecutive tiles g = wgb*ntile + ti
// (tm = g>>lgTn, tn = g & (nTn-1)) -> a block's tiles share the A-panel.
// Flat pipeline index u = ti*NT + t runs continuously across tiles: the
// vmcnt(6) cushion never drains except once at the very end. Epilogue is
// reg-only (no LDS), inserted between tiles without extra barriers; all
// sync/overwrite invariants identical to the verified 8-phase template.
// Stage slot: LDS buffer parity from UNCLAMPED slot&1; address from slot
// clamped to U-1 (dummy tail re-reads, never consumed).
// ---------------------------------------------------------------------------
template <bool GELU_OUT>
__global__ __launch_bounds__(512, 2) void gemm256(const bf16_t* __restrict__ Am,
                                                  const bf16_t* __restrict__ Bm,
                                                  const float* __restrict__ bias,
                                                  void* __restrict__ Cout,
                                                  int N, int K,
                                                  int lgNT, int lgTn, int lgNtile) {
    extern __shared__ char lds[];
    const int NT    = 1 << lgNT;        // K-tiles per output tile (K/64)
    const int ntile = 1 << lgNtile;     // output tiles per block
    const int U     = ntile << lgNT;    // total flat K-iterations

    const int tid  = threadIdx.x;
    const int lane = tid & 63;
    const int wid  = tid >> 6;
    const int wr   = wid >> 2;   // 0..1
    const int wc   = wid & 3;    // 0..3

    // XCD-aware bijective swizzle over the fixed 256-block grid (q = 32)
    const int wgb = (blockIdx.x & 7) * 32 + (blockIdx.x >> 3);

    // staging lane geometry: row_in_half = wid*8 + (lane>>3), phys slot = lane&7,
    // pre-swizzled logical col slot = (lane&7) ^ (row&7)  [row&7 == lane>>3]
    const int srow  = wid * 8 + (lane >> 3);
    const int scol8 = ((lane & 7) ^ (lane >> 3)) * 8;

    auto STAGE = [&](int isB, int half, int slot) {
        const int us  = (slot < U) ? slot : (U - 1);       // clamp tail (dummy)
        const int ti_ = us >> lgNT;
        const int kt_ = us & (NT - 1);
        const int g_  = (wgb << lgNtile) + ti_;
        const size_t base_ = (size_t)(isB ? (g_ & ((1 << lgTn) - 1)) : (g_ >> lgTn)) << 8;
        // parity from UNCLAMPED slot -> dummies land in the non-live buffer
        const unsigned reg_ = (unsigned)(((slot & 1) << 16) | (isB << 15) | (half << 14));
        const bf16_t* s0 = (isB ? Bm : Am)
                         + (base_ + (size_t)(half * 128 + srow)) * (size_t)K
                         + (size_t)((kt_ << 6) + scol8);
        __builtin_amdgcn_global_load_lds(
            (const __attribute__((address_space(1))) void*)s0,
            (__attribute__((address_space(3))) void*)(lds + reg_ + (unsigned)(wid * 1024)),
            16, 0, 0);
        __builtin_amdgcn_global_load_lds(
            (const __attribute__((address_space(1))) void*)(s0 + (size_t)64 * K),
            (__attribute__((address_space(3))) void*)(lds + reg_ + (unsigned)((8 + wid) * 1024)),
            16, 0, 0);
    };

    // M-frag m of wave wr -> tile row (m>>1)*64 + wr*32 + (m&1)*16
    auto ldsA = [&](unsigned bufo, int m, int kk) -> bf16x8 {
        const int row  = (m >> 1) * 64 + wr * 32 + (m & 1) * 16 + (lane & 15);
        const int slot = ((kk << 2) + (lane >> 4)) ^ (lane & 7);
        return *(const bf16x8*)(lds + bufo + row * 128 + slot * 16);
    };
    auto ldsB = [&](unsigned bufo, int n, int kk) -> bf16x8 {
        const int row  = wc * 64 + n * 16 + (lane & 15);
        const int slot = ((kk << 2) + (lane >> 4)) ^ (lane & 7);
        return *(const bf16x8*)(lds + bufo + 32768 + row * 128 + slot * 16);
    };

    f32x4 acc[8][4] = {};

    // Prologue: flat slots 0 (full) + 1 (partial: B0,B1,A0)
    STAGE(1, 0, 0); STAGE(1, 1, 0); STAGE(0, 0, 0); STAGE(0, 1, 0);
    STAGE(1, 0, 1); STAGE(1, 1, 1); STAGE(0, 0, 1);
    asm volatile("s_waitcnt vmcnt(6)" ::: "memory");   // slot 0 landed
    __builtin_amdgcn_s_barrier();

    for (int ti = 0; ti < ntile; ++ti) {
        for (int t = 0; t < NT; ++t) {
            const int u = (ti << lgNT) + t;
            const unsigned cur = (unsigned)(t & 1) * 65536u;   // == (u&1), NT even
            bf16x8 bf[4][2];
            bf16x8 af[2][2];

            // ---- phase 0: all B (8 reads) + A m=0,1 (4 reads); stage A1(u+1) ----
#pragma unroll
            for (int n = 0; n < 4; ++n)
#pragma unroll
                for (int kk = 0; kk < 2; ++kk)
                    bf[n][kk] = ldsB(cur, n, kk);
#pragma unroll
            for (int mm = 0; mm < 2; ++mm)
#pragma unroll
                for (int kk = 0; kk < 2; ++kk)
                    af[mm][kk] = ldsA(cur, mm, kk);
            STAGE(0, 1, u + 1);
            asm volatile("s_waitcnt lgkmcnt(8)" ::: "memory");
            __builtin_amdgcn_s_barrier();
            asm volatile("s_waitcnt lgkmcnt(0)" ::: "memory");
            __builtin_amdgcn_s_setprio(1);
#pragma unroll
            for (int mm = 0; mm < 2; ++mm)
#pragma unroll
                for (int n = 0; n < 4; ++n)
#pragma unroll
                    for (int kk = 0; kk < 2; ++kk)
                        acc[mm][n] = __builtin_amdgcn_mfma_f32_16x16x32_bf16(
                            af[mm][kk], bf[n][kk], acc[mm][n], 0, 0, 0);
            __builtin_amdgcn_s_setprio(0);
            __builtin_amdgcn_s_barrier();

            // ---- phases 1..3: A m=2p,2p+1; stage B0/B1/A0 of (u+2) ----
#pragma unroll
            for (int ph = 1; ph < 4; ++ph) {
#pragma unroll
                for (int mm = 0; mm < 2; ++mm)
#pragma unroll
                    for (int kk = 0; kk < 2; ++kk)
                        af[mm][kk] = ldsA(cur, ph * 2 + mm, kk);
                if (ph == 1)      STAGE(1, 0, u + 2);
                else if (ph == 2) STAGE(1, 1, u + 2);
                else {            STAGE(0, 0, u + 2);
                                  asm volatile("s_waitcnt vmcnt(6)" ::: "memory"); }
                __builtin_amdgcn_s_barrier();
                asm volatile("s_waitcnt lgkmcnt(0)" ::: "memory");
                __builtin_amdgcn_s_setprio(1);
#pragma unroll
                for (int mm = 0; mm < 2; ++mm)
#pragma unroll
                    for (int n = 0; n < 4; ++n)
#pragma unroll
                        for (int kk = 0; kk < 2; ++kk)
                            acc[ph * 2 + mm][n] = __builtin_amdgcn_mfma_f32_16x16x32_bf16(
                                af[mm][kk], bf[n][kk], acc[ph * 2 + mm][n], 0, 0, 0);
                __builtin_amdgcn_s_setprio(0);
                __builtin_amdgcn_s_barrier();
            }
        }

        // ---- per-tile epilogue (reg-only, no LDS; no extra barrier needed) ----
        const int g = (wgb << lgNtile) + ti;
        const size_t rowBase = (size_t)(g >> lgTn) << 8;
        const size_t colBase = (size_t)(g & ((1 << lgTn) - 1)) << 8;
        const int orow = (lane >> 4) * 4;
        const int ocol = lane & 15;
#pragma unroll
        for (int m = 0; m < 8; ++m) {
            const size_t rb = rowBase + (size_t)((m >> 1) * 64 + wr * 32 + (m & 1) * 16 + orow);
#pragma unroll
            for (int n = 0; n < 4; ++n) {
                const size_t col = colBase + (size_t)(wc * 64 + n * 16 + ocol);
                const float bv = bias[col];
#pragma unroll
                for (int j = 0; j < 4; ++j) {
                    float v = acc[m][n][j] + bv;
                    if constexpr (GELU_OUT) {
                        ((bf16_t*)Cout)[(rb + j) * (size_t)N + col] = (bf16_t)fast_gelu(v);
                    } else {
                        ((float*)Cout)[(rb + j) * (size_t)N + col] = v;
                    }
                }
                acc[m][n] = (f32x4){0.f, 0.f, 0.f, 0.f};
            }
        }
    }
    asm volatile("s_waitcnt vmcnt(0)" ::: "memory");   // drain tail dummy loads
}

// ---------------------------------------------------------------------------
extern "C" void kernel_launch(void* const* d_in, const int* in_sizes, int n_in,
                              void* d_out, int out_size, void* d_ws, size_t ws_size,
                              hipStream_t stream) {
    const float* x  = (const float*)d_in[0];  // [16384, 2048]
    const float* p1 = (const float*)d_in[1];  // [8192, 2048]
    const float* b1 = (const float*)d_in[2];  // [8192]
    const float* p2 = (const float*)d_in[3];  // [2048, 8192]
    const float* b2 = (const float*)d_in[4];  // [2048]
    // d_in[5] = gate_w, unused (routing is identity on the output)
    float* out = (float*)d_out;

    char* ws = (char*)d_ws;
    bf16_t* xb  = (bf16_t*)(ws);                          // 64 MB
    bf16_t* p1b = (bf16_t*)(ws + ((size_t)64 << 20));     // 32 MB
    bf16_t* p2b = (bf16_t*)(ws + ((size_t)96 << 20));     // 32 MB
    bf16_t* h   = (bf16_t*)(ws + ((size_t)128 << 20));    // 256 MB

    (void)hipFuncSetAttribute((const void*)gemm256<true>,
                              hipFuncAttributeMaxDynamicSharedMemorySize, 131072);
    (void)hipFuncSetAttribute((const void*)gemm256<false>,
                              hipFuncAttributeMaxDynamicSharedMemorySize, 131072);

    cvt_f32_bf16<<<2048, 256, 0, stream>>>(x,  xb,  (T_DIM * E_DIM) / 4);
    cvt_f32_bf16<<<1024, 256, 0, stream>>>(p1, p1b, (H_DIM * E_DIM) / 4);
    cvt_f32_bf16<<<1024, 256, 0, stream>>>(p2, p2b, (E_DIM * H_DIM) / 4);

    // GEMM1: [T,E] x [H,E]^T -> h[T,H]. 2048 tiles = 256 blocks x 8 tiles.
    // NT = 2048/64 = 32 (lg 5), nTn = 8192/256 = 32 (lg 5), ntile = 8 (lg 3).
    gemm256<true><<<256, 512, 131072, stream>>>(
        xb, p1b, b1, (void*)h, H_DIM, E_DIM, 5, 5, 3);

    // GEMM2: [T,H] x [E,H]^T -> out[T,E]. 512 tiles = 256 blocks x 2 tiles.
    // NT = 8192/64 = 128 (lg 7), nTn = 2048/256 = 8 (lg 3), ntile = 2 (lg 1).
    gemm256<false><<<256, 512, 131072, stream>>>(
        h, p2b, b2, (void*)out, E_DIM, H_DIM, 7, 3, 1);
}